// Round 1
// baseline (421.797 us; speedup 1.0000x reference)
//
#include <hip/hip_runtime.h>
#include <cstdint>
#include <cmath>

// RandomPhongShader: exact reproduction of JAX threefry-partitionable RNG +
// XLA CPU float32 numerics (ErfInv32 Giles poly, EmitLog1p), fused shader.
//
// Shapes: N=8,H=256,W=256,K=8, NB_SAMPLES=4. Pixels P = N*H*W = 524288.
// noise_h flat idx = s*4194304 + P*8 + k   (S,N,H,W,K)
// noise_a flat idx = s*4718592 + P*9 + j   (S,N,H,W,K+1)
// partitionable bits(i) = o0 ^ o1 of threefry2x32(key, (0, i))
// split(key(1)): kh = cipher((0,1),(0,0)), ka = cipher((0,1),(0,1))

#pragma clang fp contract(off)

#define NPIX 524288
#define STRIDE_H 4194304u
#define STRIDE_A 4718592u

__device__ __forceinline__ uint32_t rotl32(uint32_t v, int n) {
  return (v << n) | (v >> (32 - n));
}

__device__ __forceinline__ void tf2x32(uint32_t k0, uint32_t k1,
                                       uint32_t c0, uint32_t c1,
                                       uint32_t& o0, uint32_t& o1) {
  const uint32_t k2 = k0 ^ k1 ^ 0x1BD11BDAu;
  uint32_t x0 = c0 + k0, x1 = c1 + k1;
#define TFR(r) { x0 += x1; x1 = rotl32(x1, r); x1 ^= x0; }
  TFR(13) TFR(15) TFR(26) TFR(6)
  x0 += k1;  x1 += k2 + 1u;
  TFR(17) TFR(29) TFR(16) TFR(24)
  x0 += k2;  x1 += k0 + 2u;
  TFR(13) TFR(15) TFR(26) TFR(6)
  x0 += k0;  x1 += k1 + 3u;
  TFR(17) TFR(29) TFR(16) TFR(24)
  x0 += k1;  x1 += k2 + 4u;
  TFR(13) TFR(15) TFR(26) TFR(6)
  x0 += k2;  x1 += k0 + 5u;
#undef TFR
  o0 = x0; o1 = x1;
}

// bits -> N(0,1) sample, replicating jax.random.normal f32 numerics:
//   f = bitcast(bits>>9 | 0x3f800000) - 1        in [0,1)
//   u = max(lo, f*(hi-lo) + lo), lo=-0x1.fffffep-1, (hi-lo) rounds to 2.0f
//   n = f32(sqrt(2)) * erfinv(u)   [XLA ErfInv32 Giles poly, no FMA]
//   log1p per XLA EmitLog1p: |t|<1e-4 ? (1 - t/2)*t : log(1+t)
__device__ __forceinline__ float bits_to_normal(uint32_t bits) {
  float f = __uint_as_float((bits >> 9) | 0x3f800000u) - 1.0f;  // exact
  const float lo = __uint_as_float(0xBF7FFFFFu);                // -0.99999994
  float v = __fadd_rn(__fmul_rn(f, 2.0f), lo);
  v = fmaxf(lo, v);
  float t = -__fmul_rn(v, v);  // -x*x (negation exact)
  float l1p;
  if (fabsf(t) < 1e-4f) {
    l1p = __fmul_rn(__fadd_rn(__fmul_rn(-0.5f, t), 1.0f), t);
  } else {
    l1p = (float)log((double)__fadd_rn(t, 1.0f));  // correctly-rounded f32 log
  }
  float w = -l1p;
  const bool lt = w < 5.0f;
  float ww = lt ? __fsub_rn(w, 2.5f) : __fsub_rn(__fsqrt_rn(w), 3.0f);
  float p  = lt ? 2.81022636e-08f : -0.000200214257f;
  p = __fadd_rn(lt ?  3.43273939e-07f :  0.000100950558f, __fmul_rn(p, ww));
  p = __fadd_rn(lt ? -3.5233877e-06f  :  0.00134934322f,  __fmul_rn(p, ww));
  p = __fadd_rn(lt ? -4.39150654e-06f : -0.00367342844f,  __fmul_rn(p, ww));
  p = __fadd_rn(lt ?  0.00021858087f  :  0.00573950773f,  __fmul_rn(p, ww));
  p = __fadd_rn(lt ? -0.00125372503f  : -0.0076224613f,   __fmul_rn(p, ww));
  p = __fadd_rn(lt ? -0.00417768164f  :  0.00943887047f,  __fmul_rn(p, ww));
  p = __fadd_rn(lt ?  0.246640727f    :  1.00167406f,     __fmul_rn(p, ww));
  p = __fadd_rn(lt ?  1.50140941f     :  2.83297682f,     __fmul_rn(p, ww));
  // f32(sqrt(2)) = 0x3FB504F3
  return __fmul_rn(__uint_as_float(0x3FB504F3u), __fmul_rn(p, v));
}

__global__ __launch_bounds__(256) void RandomPhongShader_kernel(
    const float* __restrict__ colors,   // (P,8,3)
    const float* __restrict__ dists,    // (P,8)
    const float* __restrict__ zbuf,     // (P,8)
    const int*   __restrict__ p2f,      // (P,8)
    const float* __restrict__ bg,       // (3,)
    float* __restrict__ out)            // (P,4)
{
  const int P = blockIdx.x * 256 + threadIdx.x;
  if (P >= NPIX) return;

  // Derive kh/ka from root key (0,1) via fold-like split (partitionable).
  uint32_t kh0, kh1, ka0, ka1;
  tf2x32(0u, 1u, 0u, 0u, kh0, kh1);
  tf2x32(0u, 1u, 0u, 1u, ka0, ka1);

  // ---- loads (vectorized) ----
  float dk[8], zk[8];
  int mk[8];
  {
    const float4* d4 = reinterpret_cast<const float4*>(dists + (size_t)P * 8);
    float4 a = d4[0], b = d4[1];
    dk[0]=a.x; dk[1]=a.y; dk[2]=a.z; dk[3]=a.w; dk[4]=b.x; dk[5]=b.y; dk[6]=b.z; dk[7]=b.w;
    const float4* z4 = reinterpret_cast<const float4*>(zbuf + (size_t)P * 8);
    float4 c = z4[0], e = z4[1];
    zk[0]=c.x; zk[1]=c.y; zk[2]=c.z; zk[3]=c.w; zk[4]=e.x; zk[5]=e.y; zk[6]=e.z; zk[7]=e.w;
    const int4* m4 = reinterpret_cast<const int4*>(p2f + (size_t)P * 8);
    int4 f = m4[0], g = m4[1];
    mk[0]=f.x; mk[1]=f.y; mk[2]=f.z; mk[3]=f.w; mk[4]=g.x; mk[5]=g.y; mk[6]=g.z; mk[7]=g.w;
  }

  // ---- prob_map via random_heaviside; alpha product (all values exact) ----
  const uint32_t baseH = (uint32_t)P * 8u;
  int li[8];           // index into log table = 4*prob_map
  float alpha = 1.0f;
  #pragma unroll
  for (int k = 0; k < 8; ++k) {
    const float x = -dk[k];
    int cnt = 0;
    #pragma unroll
    for (int s = 0; s < 4; ++s) {
      uint32_t o0, o1;
      tf2x32(kh0, kh1, 0u, (uint32_t)s * STRIDE_H + baseH + (uint32_t)k, o0, o1);
      float nz = bits_to_normal(o0 ^ o1);
      cnt += (__fadd_rn(x, __fmul_rn(0.1f, nz)) >= 0.0f) ? 1 : 0;
    }
    const float m = (mk[k] >= 0) ? 1.0f : 0.0f;
    const float pm = __fmul_rn(__fmul_rn((float)cnt, 0.25f), m);
    li[k] = (m != 0.0f) ? cnt : 0;
    alpha *= (1.0f - pm);  // products of {0,.25,.5,.75,1} complements: exact
  }

  // ---- z_inv, z_inv_max ----
  float zinv[8], zmax;
  #pragma unroll
  for (int k = 0; k < 8; ++k) {
    const float m = (mk[k] >= 0) ? 1.0f : 0.0f;
    float zi = __fmul_rn(__fdiv_rn(__fsub_rn(100.0f, zk[k]), 99.0f), m);
    zinv[k] = zi;
    zmax = (k == 0) ? zi : fmaxf(zmax, zi);
  }
  zmax = fmaxf(zmax, 1e-10f);  // jnp.clip(max, EPS)

  // log(EPS + prob) has only 5 possible inputs; EPS is absorbed except prob=0.
  const float lg0 = (float)log((double)1e-10f);
  const float lg1 = (float)log(0.25);
  const float lg2 = (float)log(0.5);
  const float lg3 = (float)log(0.75);

  float zm[9];
  #pragma unroll
  for (int k = 0; k < 8; ++k) {
    const int i = li[k];
    const float lg = (i == 0) ? lg0 : (i == 1) ? lg1 : (i == 2) ? lg2
                   : (i == 3) ? lg3 : 0.0f;
    zm[k] = __fadd_rn(lg, __fdiv_rn(__fsub_rn(zinv[k], zmax), 0.1f));
  }
  zm[8] = __fdiv_rn(__fsub_rn(1e-10f, zmax), 0.1f);  // bg_score

  // ---- random_argmax over K+1=9 channels, 4 samples ----
  float wgt[9] = {0.f,0.f,0.f,0.f,0.f,0.f,0.f,0.f,0.f};
  const uint32_t baseA = (uint32_t)P * 9u;
  #pragma unroll
  for (int s = 0; s < 4; ++s) {
    int am = 0;
    float best = 0.0f;
    #pragma unroll
    for (int j = 0; j < 9; ++j) {
      uint32_t o0, o1;
      tf2x32(ka0, ka1, 0u, (uint32_t)s * STRIDE_A + baseA + (uint32_t)j, o0, o1);
      float nz = bits_to_normal(o0 ^ o1);
      float v = __fadd_rn(zm[j], __fmul_rn(0.1f, nz));
      if (j == 0) { best = v; am = 0; }
      else if (v > best) { best = v; am = j; }  // strict > == first-max tiebreak
    }
    #pragma unroll
    for (int j = 0; j < 9; ++j) wgt[j] += (am == j) ? 0.25f : 0.0f;  // exact
  }

  // ---- epilogue: weighted colors + background, alpha channel ----
  float cc[24];
  {
    const float4* c4 = reinterpret_cast<const float4*>(colors + (size_t)P * 24);
    #pragma unroll
    for (int q = 0; q < 6; ++q) {
      float4 t = c4[q];
      cc[q*4+0]=t.x; cc[q*4+1]=t.y; cc[q*4+2]=t.z; cc[q*4+3]=t.w;
    }
  }
  float rgb[3];
  #pragma unroll
  for (int c = 0; c < 3; ++c) {
    float acc = 0.0f;
    #pragma unroll
    for (int k = 0; k < 8; ++k)
      acc = __fadd_rn(acc, __fmul_rn(wgt[k], cc[k * 3 + c]));
    rgb[c] = __fadd_rn(acc, __fmul_rn(wgt[8], bg[c]));
  }

  float4 o;
  o.x = rgb[0]; o.y = rgb[1]; o.z = rgb[2];
  o.w = __fsub_rn(1.0f, alpha);
  reinterpret_cast<float4*>(out)[P] = o;
}

extern "C" void kernel_launch(void* const* d_in, const int* in_sizes, int n_in,
                              void* d_out, int out_size, void* d_ws, size_t ws_size,
                              hipStream_t stream) {
  const float* colors = (const float*)d_in[0];
  const float* dists  = (const float*)d_in[1];
  const float* zbuf   = (const float*)d_in[2];
  const int*   p2f    = (const int*)d_in[3];
  const float* bg     = (const float*)d_in[4];
  float* out = (float*)d_out;
  dim3 grid(NPIX / 256), block(256);
  hipLaunchKernelGGL(RandomPhongShader_kernel, grid, block, 0, stream,
                     colors, dists, zbuf, p2f, bg, out);
}